// Round 7
// baseline (346.878 us; speedup 1.0000x reference)
//
#include <hip/hip_runtime.h>
#include <hip/hip_cooperative_groups.h>
#include <hip/hip_bf16.h>

namespace cg = cooperative_groups;

#define D 128

// ---------------------------------------------------------------------------
// Single cooperative kernel, 4 phases separated by grid.sync():
//  A: blocks 0..7 compute b_w = b_alpha^T W_alpha (16 cols each).
//     (c = (a_alpha^T W_alpha).X[0] cancels in the normalization — dead.)
//  B: all blocks stream X once: alpha_j = exp(b_w.X[j]); accumulate
//     alpha_j * X[j] and alpha_j (grid-stride, 2 rows per 32-lane subgroup,
//     depth-1 prefetch, branchless).
//  C1: blocks 0..63 tree-reduce the NB block-partials (block 0 also sums
//      the alpha partials).
//  C2: block 0 normalizes and applies W_sum.
// All reduction orders fixed -> deterministic.
// ---------------------------------------------------------------------------
__global__ __launch_bounds__(256, 8) void fused_all_kernel(
    const float* __restrict__ X,
    const float* __restrict__ W_alpha,
    const float* __restrict__ b_alpha,
    const float* __restrict__ W_sum,
    float* __restrict__ out,
    float* __restrict__ bw,       // [D]
    float* __restrict__ pw,       // [NB][D]
    float* __restrict__ pa,       // [NB]
    float* __restrict__ mid,      // [64][D]
    float* __restrict__ mida,     // [1]
    int nrows)
{
    cg::grid_group grid = cg::this_grid();
    const int t  = threadIdx.x;
    const int b  = blockIdx.x;
    const int NB = gridDim.x;

    // ---------------- Phase A: b_w (blocks 0..7) ----------------
    if (b < 8) {
        const int kk = b * 16 + (t & 15);   // output column
        const int gg = t >> 4;              // 0..15: 8 i-terms each
        float s = 0.f;
        #pragma unroll
        for (int i = gg * 8; i < gg * 8 + 8; ++i)
            s = fmaf(b_alpha[i], W_alpha[i * D + kk], s);
        __shared__ float sA[16][17];
        sA[gg][t & 15] = s;
        __syncthreads();
        if (t < 16) {
            float r = 0.f;
            #pragma unroll
            for (int g2 = 0; g2 < 16; ++g2) r += sA[g2][t];
            bw[b * 16 + t] = r;
        }
        __threadfence();
    }
    grid.sync();

    // ---------------- Phase B: main streaming pass ----------------
    const int col4 = t & 31;   // which float4 of the row
    const int rg   = t >> 5;   // row-group 0..7 within the block

    const float4 bwv = reinterpret_cast<const float4*>(bw)[col4];

    float a0 = 0.f, a1 = 0.f, a2 = 0.f, a3 = 0.f;
    float aacc = 0.f;

    const int ftiles = nrows >> 4;          // full 16-row tiles
    const float4* __restrict__ X4 = reinterpret_cast<const float4*>(X);
    const int    gstep = NB;
    const size_t step  = (size_t)gstep * 512;   // float4 units per stride

    int tile = b;
    if (tile < ftiles) {
        size_t addr = ((size_t)tile * 16 + rg * 2) * 32 + col4;
        float4 x0 = X4[addr];
        float4 x1 = X4[addr + 32];

        while (tile < ftiles) {
            const int ntile = tile + gstep;
            const size_t naddr = addr + (ntile < ftiles ? step : (size_t)0);
            const float4 n0 = X4[naddr];          // clamped prefetch
            const float4 n1 = X4[naddr + 32];

            float d0 = fmaf(x0.x, bwv.x, fmaf(x0.y, bwv.y, fmaf(x0.z, bwv.z, x0.w * bwv.w)));
            float d1 = fmaf(x1.x, bwv.x, fmaf(x1.y, bwv.y, fmaf(x1.z, bwv.z, x1.w * bwv.w)));
            #pragma unroll
            for (int m = 16; m >= 1; m >>= 1) {
                d0 += __shfl_xor(d0, m, 64);
                d1 += __shfl_xor(d1, m, 64);
            }
            const float al0 = __expf(d0);
            const float al1 = __expf(d1);
            aacc += al0 + al1;                    // uniform across 32 lanes
            a0 = fmaf(al0, x0.x, fmaf(al1, x1.x, a0));
            a1 = fmaf(al0, x0.y, fmaf(al1, x1.y, a1));
            a2 = fmaf(al0, x0.z, fmaf(al1, x1.z, a2));
            a3 = fmaf(al0, x0.w, fmaf(al1, x1.w, a3));

            x0 = n0; x1 = n1; addr = naddr; tile = ntile;
        }
    }

    // remainder rows (nrows % 16): block 0 only — dead for N=200000
    const int rem = nrows & 15;
    if (rem && b == 0) {
        const int r0 = (nrows & ~15) + rg * 2;
        if (r0 < nrows) {
            const float4 x0r = X4[(size_t)r0 * 32 + col4];
            const bool v1 = (r0 + 1) < nrows;
            const float4 x1r = v1 ? X4[(size_t)(r0 + 1) * 32 + col4]
                                  : make_float4(0.f, 0.f, 0.f, 0.f);
            float d0 = fmaf(x0r.x, bwv.x, fmaf(x0r.y, bwv.y, fmaf(x0r.z, bwv.z, x0r.w * bwv.w)));
            float d1 = fmaf(x1r.x, bwv.x, fmaf(x1r.y, bwv.y, fmaf(x1r.z, bwv.z, x1r.w * bwv.w)));
            #pragma unroll
            for (int m = 16; m >= 1; m >>= 1) {
                d0 += __shfl_xor(d0, m, 64);
                d1 += __shfl_xor(d1, m, 64);
            }
            const float al0 = __expf(d0);
            const float al1 = v1 ? __expf(d1) : 0.f;
            aacc += al0 + al1;
            a0 = fmaf(al0, x0r.x, fmaf(al1, x1r.x, a0));
            a1 = fmaf(al0, x0r.y, fmaf(al1, x1r.y, a1));
            a2 = fmaf(al0, x0r.z, fmaf(al1, x1r.z, a2));
            a3 = fmaf(al0, x0r.w, fmaf(al1, x1r.w, a3));
        }
    }

    // block reduction (8 row-groups -> one 128-vector)
    __shared__ float red[8][32][4];   // 4 KB
    __shared__ float reda[8];
    red[rg][col4][0] = a0;
    red[rg][col4][1] = a1;
    red[rg][col4][2] = a2;
    red[rg][col4][3] = a3;
    if (col4 == 0) reda[rg] = aacc;
    __syncthreads();

    if (t < D) {
        float s = 0.f;
        #pragma unroll
        for (int r = 0; r < 8; ++r) s += red[r][t >> 2][t & 3];
        pw[(size_t)b * D + t] = s;
    }
    if (t == 0) {
        float s = 0.f;
        #pragma unroll
        for (int r = 0; r < 8; ++r) s += reda[r];
        pa[b] = s;
    }
    __threadfence();
    grid.sync();

    // ---------------- Phase C1: blocks 0..63 reduce partials ----------------
    if (b < 64) {
        const int k = t & 127;
        const int h = t >> 7;     // 0..1
        double accw = 0.0;
        for (int r = b + 64 * h; r < NB; r += 128)
            accw += (double)pw[(size_t)r * D + k];   // coalesced across k
        __shared__ double sw1[2][D];   // 2 KB
        sw1[h][k] = accw;

        __shared__ double sa1[256];    // 2 KB
        if (b == 0) {
            double acca = 0.0;
            for (int r = t; r < NB; r += 256) acca += (double)pa[r];
            sa1[t] = acca;
        }
        __syncthreads();

        if (t < D)
            mid[(size_t)b * D + t] = (float)(sw1[0][t] + sw1[1][t]);
        if (b == 0) {
            #pragma unroll
            for (int s = 128; s >= 1; s >>= 1) {
                if (t < s) sa1[t] += sa1[t + s];
                __syncthreads();
            }
            if (t == 0) mida[0] = (float)sa1[0];
        }
        __threadfence();
    }
    grid.sync();

    // ---------------- Phase C2: block 0 normalizes + W_sum ----------------
    if (b == 0) {
        const int k = t & 127;
        const int g = t >> 7;     // 0..1
        double s = 0.0;
        for (int r = g * 32; r < g * 32 + 32; ++r)
            s += (double)mid[(size_t)r * D + k];     // coalesced across k
        __shared__ double sw2[2][D];   // 2 KB
        sw2[g][k] = s;
        __syncthreads();

        const double asum = (double)mida[0];
        __shared__ float ssh[D];
        if (t < D) ssh[t] = (float)((sw2[0][t] + sw2[1][t]) / asum);
        __syncthreads();

        float o = 0.f;
        #pragma unroll 8
        for (int kk = g * 64; kk < g * 64 + 64; ++kk)
            o = fmaf(ssh[kk], W_sum[kk * D + k], o); // coalesced across k
        __shared__ float ro[2][D];
        ro[g][k] = o;
        __syncthreads();
        if (t < D) out[t] = ro[0][t] + ro[1][t];
    }
}

// ---------------------------------------------------------------------------
extern "C" void kernel_launch(void* const* d_in, const int* in_sizes, int n_in,
                              void* d_out, int out_size, void* d_ws, size_t ws_size,
                              hipStream_t stream) {
    const float* X       = (const float*)d_in[0];
    const float* W_sum   = (const float*)d_in[1];
    const float* W_alpha = (const float*)d_in[2];
    const float* b_alpha = (const float*)d_in[4];
    float* out = (float*)d_out;

    const int nrows = in_sizes[0] / D;   // 200000

    // grid size: co-resident occupancy (deterministic queries)
    int perCU = 0;
    hipOccupancyMaxActiveBlocksPerMultiprocessor(&perCU, fused_all_kernel, 256, 0);
    int nCU = 0;
    hipDeviceGetAttribute(&nCU, hipDeviceAttributeMultiprocessorCount, 0);
    if (perCU < 1) perCU = 1;
    if (nCU < 1) nCU = 256;
    int NB = perCU * nCU;
    if (NB > 2048) NB = 2048;
    if (NB < 64)  NB = 64;

    auto need = [&](int nb) {
        return (size_t)nb * (D + 1) * sizeof(float)       // pw + pa
             + 512
             + (size_t)64 * D * sizeof(float) + 64        // mid + mida
             + (D + 8) * sizeof(float);                    // bw
    };
    while (NB > 64 && need(NB) > ws_size) NB >>= 1;

    char* ws = (char*)d_ws;
    float* pw   = (float*)ws;
    float* pa   = pw + (size_t)NB * D;
    size_t off = ((size_t)NB * (D + 1) * sizeof(float) + 255) & ~(size_t)255;
    float* mid  = (float*)(ws + off);
    float* mida = mid + (size_t)64 * D;
    float* bw   = mida + 16;   // keep 16B alignment for float4 reads

    void* args[] = { (void*)&X, (void*)&W_alpha, (void*)&b_alpha,
                     (void*)&W_sum, (void*)&out, (void*)&bw, (void*)&pw,
                     (void*)&pa, (void*)&mid, (void*)&mida, (void*)&nrows };
    hipLaunchCooperativeKernel((const void*)fused_all_kernel,
                               dim3(NB), dim3(256), args, 0, stream);
}

// Round 8
// 52.777 us; speedup vs baseline: 6.5725x; 6.5725x over previous
//
#include <hip/hip_runtime.h>
#include <hip/hip_bf16.h>

#define D 128

// ---------------------------------------------------------------------------
// R8 = R5 structure EXACTLY, with the main pass dispatched TWICE (second
// dispatch stores bit-identical partials over the first). Pure timing probe:
// T_R8 - T_R5 = main_dur + one inter-dispatch gap. Output bit-identical.
// ---------------------------------------------------------------------------

// Kernel 1 (1 block, 1024 threads): b_w = b_alpha^T @ W_alpha.
__global__ __launch_bounds__(1024) void prep_kernel(
    const float* __restrict__ W_alpha,
    const float* __restrict__ b_alpha,
    float* __restrict__ bw_out)   // [D]
{
    const int t = threadIdx.x;
    const int k = t & 127;        // output column
    const int g = t >> 7;         // 0..7: 16 i-terms each
    __shared__ float bal[D];
    if (t < D) bal[t] = b_alpha[t];
    __syncthreads();

    float bw = 0.f;
    #pragma unroll
    for (int i = g * 16; i < g * 16 + 16; ++i)
        bw = fmaf(bal[i], W_alpha[i * D + k], bw);   // coalesced across k

    __shared__ float rbw[8][D];
    rbw[g][k] = bw;
    __syncthreads();
    if (t < D) {
        float B = 0.f;
        #pragma unroll
        for (int r = 0; r < 8; ++r) B += rbw[r][t];
        bw_out[t] = B;
    }
}

// ---------------------------------------------------------------------------
// Kernel 2 (main pass): identical to R5. Branchless streaming, 2 rows per
// 32-lane subgroup, depth-1 clamped prefetch.
// ---------------------------------------------------------------------------
__global__ __launch_bounds__(256, 8) void main_pass_kernel(
    const float* __restrict__ X,
    const float* __restrict__ bw,
    float* __restrict__ partial_wsum,    // [gridDim.x][D]
    float* __restrict__ partial_alpha,   // [gridDim.x]
    int nrows)
{
    const int t    = threadIdx.x;
    const int col4 = t & 31;   // which float4 of the row
    const int rg   = t >> 5;   // row-group 0..7 within the block

    const float4 bwv = reinterpret_cast<const float4*>(bw)[col4];

    float a0 = 0.f, a1 = 0.f, a2 = 0.f, a3 = 0.f;
    float aacc = 0.f;

    const int ftiles = nrows >> 4;          // full 16-row tiles
    const float4* __restrict__ X4 = reinterpret_cast<const float4*>(X);
    const int    gstep = gridDim.x;
    const size_t step  = (size_t)gstep * 512;   // float4 units per stride

    int tile = blockIdx.x;
    if (tile < ftiles) {
        size_t addr = ((size_t)tile * 16 + rg * 2) * 32 + col4;
        float4 x0 = X4[addr];
        float4 x1 = X4[addr + 32];

        while (tile < ftiles) {
            const int ntile = tile + gstep;
            const size_t naddr = addr + (ntile < ftiles ? step : (size_t)0);
            const float4 n0 = X4[naddr];          // clamped prefetch
            const float4 n1 = X4[naddr + 32];

            float d0 = fmaf(x0.x, bwv.x, fmaf(x0.y, bwv.y, fmaf(x0.z, bwv.z, x0.w * bwv.w)));
            float d1 = fmaf(x1.x, bwv.x, fmaf(x1.y, bwv.y, fmaf(x1.z, bwv.z, x1.w * bwv.w)));
            #pragma unroll
            for (int m = 16; m >= 1; m >>= 1) {
                d0 += __shfl_xor(d0, m, 64);
                d1 += __shfl_xor(d1, m, 64);
            }
            const float al0 = __expf(d0);
            const float al1 = __expf(d1);
            aacc += al0 + al1;                    // uniform across the 32 lanes
            a0 = fmaf(al0, x0.x, fmaf(al1, x1.x, a0));
            a1 = fmaf(al0, x0.y, fmaf(al1, x1.y, a1));
            a2 = fmaf(al0, x0.z, fmaf(al1, x1.z, a2));
            a3 = fmaf(al0, x0.w, fmaf(al1, x1.w, a3));

            x0 = n0; x1 = n1; addr = naddr; tile = ntile;
        }
    }

    // remainder rows (nrows % 16): block 0 only — dead for N=200000
    const int rem = nrows & 15;
    if (rem && blockIdx.x == 0) {
        const int r0 = (nrows & ~15) + rg * 2;
        if (r0 < nrows) {
            const float4 x0r = X4[(size_t)r0 * 32 + col4];
            const bool v1 = (r0 + 1) < nrows;
            const float4 x1r = v1 ? X4[(size_t)(r0 + 1) * 32 + col4]
                                  : make_float4(0.f, 0.f, 0.f, 0.f);
            float d0 = fmaf(x0r.x, bwv.x, fmaf(x0r.y, bwv.y, fmaf(x0r.z, bwv.z, x0r.w * bwv.w)));
            float d1 = fmaf(x1r.x, bwv.x, fmaf(x1r.y, bwv.y, fmaf(x1r.z, bwv.z, x1r.w * bwv.w)));
            #pragma unroll
            for (int m = 16; m >= 1; m >>= 1) {
                d0 += __shfl_xor(d0, m, 64);
                d1 += __shfl_xor(d1, m, 64);
            }
            const float al0 = __expf(d0);
            const float al1 = v1 ? __expf(d1) : 0.f;
            aacc += al0 + al1;
            a0 = fmaf(al0, x0r.x, fmaf(al1, x1r.x, a0));
            a1 = fmaf(al0, x0r.y, fmaf(al1, x1r.y, a1));
            a2 = fmaf(al0, x0r.z, fmaf(al1, x1r.z, a2));
            a3 = fmaf(al0, x0r.w, fmaf(al1, x1r.w, a3));
        }
    }

    // -------- block reduction (8 row-groups -> one 128-vector) --------
    __shared__ float red[8][32][4];   // 4 KB
    __shared__ float reda[8];
    red[rg][col4][0] = a0;
    red[rg][col4][1] = a1;
    red[rg][col4][2] = a2;
    red[rg][col4][3] = a3;
    if (col4 == 0) reda[rg] = aacc;
    __syncthreads();

    if (t < D) {
        float s = 0.f;
        #pragma unroll
        for (int r = 0; r < 8; ++r) s += red[r][t >> 2][t & 3];
        partial_wsum[(size_t)blockIdx.x * D + t] = s;
    }
    if (t == 0) {
        float s = 0.f;
        #pragma unroll
        for (int r = 0; r < 8; ++r) s += reda[r];
        partial_alpha[blockIdx.x] = s;
    }
}

// ---------------------------------------------------------------------------
// Kernel 3 (NB2 blocks, 512 threads): tree-reduce block partials to float.
// ---------------------------------------------------------------------------
__global__ __launch_bounds__(512) void reduce1_kernel(
    const float* __restrict__ partial_wsum,
    const float* __restrict__ partial_alpha,
    float* __restrict__ mid,      // [NB2][D]
    float* __restrict__ mida,     // [NB2]
    int NB, int NB2)
{
    const int b  = blockIdx.x;
    const int t  = threadIdx.x;
    const int k  = t & 127;
    const int rs = t >> 7;        // 0..3
    const int nper = NB / NB2;

    double s = 0.0;
    for (int j = rs; j < nper; j += 4)
        s += (double)partial_wsum[(size_t)(b + NB2 * j) * D + k];  // coalesced
    __shared__ double red[4][D];  // 4 KB
    red[rs][k] = s;

    __shared__ double reda[64];
    if (t < 64) {
        double sa = 0.0;
        for (int j = t; j < nper; j += 64) sa += (double)partial_alpha[b + NB2 * j];
        reda[t] = sa;
    }
    __syncthreads();

    if (t < D)
        mid[(size_t)b * D + t] = (float)(red[0][t] + red[1][t] + red[2][t] + red[3][t]);
    if (t == 0) {
        double sa = 0.0;
        const int lim = nper < 64 ? nper : 64;
        for (int i = 0; i < lim; ++i) sa += reda[i];
        mida[b] = (float)sa;
    }
}

// ---------------------------------------------------------------------------
// Kernel 4 (1 block, 1024 threads): final reduce, normalize, @ W_sum.
// ---------------------------------------------------------------------------
__global__ __launch_bounds__(1024) void final_kernel(
    const float* __restrict__ mid,
    const float* __restrict__ mida,
    const float* __restrict__ W_sum,
    float* __restrict__ out,
    int NB2)
{
    const int t = threadIdx.x;
    const int k = t & 127;
    const int g = t >> 7;     // 0..7

    // --- issue W_sum loads early (4 float4 per thread, coalesced) ---
    const float4* __restrict__ W4 = reinterpret_cast<const float4*>(W_sum);
    float4 w0 = W4[t], w1 = W4[t + 1024], w2 = W4[t + 2048], w3 = W4[t + 3072];

    // --- reduce mid partials while W_sum is in flight ---
    __shared__ float red[8][D];     // 4 KB
    float ws = 0.f;
    #pragma unroll
    for (int j = 0; j < 8; ++j) {
        const int row = g + j * 8;
        if (row < NB2) ws += mid[(size_t)row * D + k];
    }
    red[g][k] = ws;

    __shared__ float reda[64];
    if (t < 64) reda[t] = (t < NB2) ? mida[t] : 0.f;

    // --- stage W_sum to LDS ---
    __shared__ float wls[D * D];    // 64 KB
    float4* wls4 = reinterpret_cast<float4*>(wls);
    wls4[t] = w0; wls4[t + 1024] = w1; wls4[t + 2048] = w2; wls4[t + 3072] = w3;
    __syncthreads();

    __shared__ double asum_sh;
    if (t == 0) {
        double a = 0.0;
        #pragma unroll
        for (int i = 0; i < 64; ++i) a += (double)reda[i];
        asum_sh = a;
    }
    __syncthreads();

    __shared__ float s_sh[D];
    if (t < D) {
        double s = 0.0;
        #pragma unroll
        for (int r = 0; r < 8; ++r) s += (double)red[r][t];
        s_sh[t] = (float)(s / asum_sh);
    }
    __syncthreads();

    // out[j] = sum_k s[k] * W_sum[k][j], split over the 8 groups
    float o = 0.f;
    #pragma unroll
    for (int kk = g * 16; kk < g * 16 + 16; ++kk)
        o = fmaf(s_sh[kk], wls[kk * D + k], o);
    __shared__ float rout[8][D];    // 4 KB
    rout[g][k] = o;
    __syncthreads();
    if (t < D) {
        float s = 0.f;
        #pragma unroll
        for (int r = 0; r < 8; ++r) s += rout[r][t];
        out[t] = s;
    }
}

// ---------------------------------------------------------------------------
extern "C" void kernel_launch(void* const* d_in, const int* in_sizes, int n_in,
                              void* d_out, int out_size, void* d_ws, size_t ws_size,
                              hipStream_t stream) {
    const float* X       = (const float*)d_in[0];
    const float* W_sum   = (const float*)d_in[1];
    const float* W_alpha = (const float*)d_in[2];
    const float* b_alpha = (const float*)d_in[4];
    float* out = (float*)d_out;

    const int nrows = in_sizes[0] / D;   // 200000
    const int NB2 = 64;

    int NB = 2048;
    auto need = [&](int nb) {
        return (size_t)nb * (D + 1) * sizeof(float)     // partials
             + 256
             + (size_t)NB2 * (D + 1) * sizeof(float)    // mid + mida
             + (D + 8) * sizeof(float);
    };
    while (NB > NB2 && need(NB) > ws_size) NB >>= 1;

    char* ws = (char*)d_ws;
    float* partial_wsum  = (float*)ws;
    float* partial_alpha = (float*)(ws + (size_t)NB * D * sizeof(float));
    size_t off = (size_t)NB * (D + 1) * sizeof(float);
    off = (off + 255) & ~(size_t)255;
    float* mid  = (float*)(ws + off);
    float* mida = mid + (size_t)NB2 * D;
    float* bw   = mida + NB2;

    prep_kernel<<<1, 1024, 0, stream>>>(W_alpha, b_alpha, bw);
    // PROBE: main pass dispatched twice — second stores bit-identical
    // partials over the first. T_R8 - T_R5 = main_dur + one gap.
    main_pass_kernel<<<NB, 256, 0, stream>>>(X, bw, partial_wsum,
                                             partial_alpha, nrows);
    main_pass_kernel<<<NB, 256, 0, stream>>>(X, bw, partial_wsum,
                                             partial_alpha, nrows);
    reduce1_kernel<<<NB2, 512, 0, stream>>>(partial_wsum, partial_alpha,
                                            mid, mida, NB, NB2);
    final_kernel<<<1, 1024, 0, stream>>>(mid, mida, W_sum, out, NB2);
}